// Round 1
// baseline (467.870 us; speedup 1.0000x reference)
//
#include <hip/hip_runtime.h>

// HiPPO-LegS scan, fp32 chunked associative scan.
// s_t = A_t s_{t-1} + u_t,  u_t[b,n] = x[t,b]*Bv[t,n],  out[t,b,n] = s_t[n] (per batch b).
// N=128, B=32, L=1024. Chunks of T=4 (C=256). Up-tree to level 5 (8 nodes of 128 steps).
// Workspace: 504 "units" of (M 128x128 | W 128x32) fp32 = 41.3 MB of d_ws.

#define NN   128
#define NB   32
#define LL   1024
#define TCH  4
#define NCH  256
#define LDP  160   // P row stride (128 matrix cols + 32 state cols), 16B-aligned rows
#define LDA  132   // staged A-tile row stride (16 x 132), padded vs bank conflicts
#define LDS_S 36   // state tile row stride (128 x 36), 16B-aligned rows
#define UNIT 20480 // floats per unit: 128*128 + 128*32

// ---------------------------------------------------------------------------
// P (LDS, 128 x LDP) <- Ag (global 128x128, row-major) * P   (augmented, in place)
// 256 threads: thread (ti=tid>>4, tj=tid&15) owns rows ti*8..+7, cols tj*4..+3,
// 64+tj*4..+3 (matrix part) and 128+tj*2..+1 (state part).
__device__ __forceinline__ void aug_matmul(const float* __restrict__ Ag,
                                           float* __restrict__ P,
                                           float* __restrict__ As) {
  const int tid = threadIdx.x;
  const int ti = tid >> 4;
  const int tj = tid & 15;
  const int i0 = ti * 8;
  float accA[8][4], accB[8][4], accS[8][2];
#pragma unroll
  for (int r = 0; r < 8; ++r) {
#pragma unroll
    for (int q = 0; q < 4; ++q) { accA[r][q] = 0.f; accB[r][q] = 0.f; }
    accS[r][0] = 0.f; accS[r][1] = 0.f;
  }
  for (int kt = 0; kt < 8; ++kt) {
    __syncthreads();
    {  // stage As[kk][i] = Ag[i][kt*16+kk]  (transposed so FMA-loop reads are contiguous)
      const int q = tid & 3;
      const int ib = tid >> 2;  // 0..63
#pragma unroll
      for (int h = 0; h < 2; ++h) {
        const int i = ib + 64 * h;
        const float4 v = *(const float4*)(Ag + i * NN + kt * 16 + q * 4);
        As[(q * 4 + 0) * LDA + i] = v.x;
        As[(q * 4 + 1) * LDA + i] = v.y;
        As[(q * 4 + 2) * LDA + i] = v.z;
        As[(q * 4 + 3) * LDA + i] = v.w;
      }
    }
    __syncthreads();
#pragma unroll
    for (int kk = 0; kk < 16; ++kk) {
      const int k = kt * 16 + kk;
      const float4 a0 = *(const float4*)(As + kk * LDA + i0);
      const float4 a1 = *(const float4*)(As + kk * LDA + i0 + 4);
      const float4 p0 = *(const float4*)(P + k * LDP + tj * 4);
      const float4 p1 = *(const float4*)(P + k * LDP + 64 + tj * 4);
      const float2 ps = *(const float2*)(P + k * LDP + 128 + tj * 2);
      const float ar[8] = {a0.x, a0.y, a0.z, a0.w, a1.x, a1.y, a1.z, a1.w};
#pragma unroll
      for (int r = 0; r < 8; ++r) {
        accA[r][0] += ar[r] * p0.x; accA[r][1] += ar[r] * p0.y;
        accA[r][2] += ar[r] * p0.z; accA[r][3] += ar[r] * p0.w;
        accB[r][0] += ar[r] * p1.x; accB[r][1] += ar[r] * p1.y;
        accB[r][2] += ar[r] * p1.z; accB[r][3] += ar[r] * p1.w;
        accS[r][0] += ar[r] * ps.x; accS[r][1] += ar[r] * ps.y;
      }
    }
  }
  __syncthreads();
#pragma unroll
  for (int r = 0; r < 8; ++r) {
    *(float4*)(P + (i0 + r) * LDP + tj * 4) =
        make_float4(accA[r][0], accA[r][1], accA[r][2], accA[r][3]);
    *(float4*)(P + (i0 + r) * LDP + 64 + tj * 4) =
        make_float4(accB[r][0], accB[r][1], accB[r][2], accB[r][3]);
    *(float2*)(P + (i0 + r) * LDP + 128 + tj * 2) =
        make_float2(accS[r][0], accS[r][1]);
  }
  __syncthreads();
}

// ---------------------------------------------------------------------------
// S (LDS, 128 x LDS_S, state as S[n][b]) <- Mg (global 128x128) * S   (in place)
// 128 threads: thread (ri=tid>>3, tb=tid&7) owns rows ri*8..+7, cols tb*4..+3.
__device__ __forceinline__ void apply_op(const float* __restrict__ Mg,
                                         float* __restrict__ S,
                                         float* __restrict__ As) {
  const int tid = threadIdx.x;
  const int ri = tid >> 3;
  const int tb = tid & 7;
  const int i0 = ri * 8;
  const int b0 = tb * 4;
  float acc[8][4];
#pragma unroll
  for (int r = 0; r < 8; ++r)
#pragma unroll
    for (int q = 0; q < 4; ++q) acc[r][q] = 0.f;
  for (int kt = 0; kt < 8; ++kt) {
    __syncthreads();
    {
      const int q = tid & 3;
      const int ib = tid >> 2;  // 0..31
#pragma unroll
      for (int h = 0; h < 4; ++h) {
        const int i = ib + 32 * h;
        const float4 v = *(const float4*)(Mg + i * NN + kt * 16 + q * 4);
        As[(q * 4 + 0) * LDA + i] = v.x;
        As[(q * 4 + 1) * LDA + i] = v.y;
        As[(q * 4 + 2) * LDA + i] = v.z;
        As[(q * 4 + 3) * LDA + i] = v.w;
      }
    }
    __syncthreads();
#pragma unroll
    for (int kk = 0; kk < 16; ++kk) {
      const int k = kt * 16 + kk;
      const float4 a0 = *(const float4*)(As + kk * LDA + i0);
      const float4 a1 = *(const float4*)(As + kk * LDA + i0 + 4);
      const float4 sv = *(const float4*)(S + k * LDS_S + b0);
      const float ar[8] = {a0.x, a0.y, a0.z, a0.w, a1.x, a1.y, a1.z, a1.w};
#pragma unroll
      for (int r = 0; r < 8; ++r) {
        acc[r][0] += ar[r] * sv.x; acc[r][1] += ar[r] * sv.y;
        acc[r][2] += ar[r] * sv.z; acc[r][3] += ar[r] * sv.w;
      }
    }
  }
  __syncthreads();
#pragma unroll
  for (int r = 0; r < 8; ++r)
    *(float4*)(S + (i0 + r) * LDS_S + b0) =
        make_float4(acc[r][0], acc[r][1], acc[r][2], acc[r][3]);
  __syncthreads();
}

// ---------------------------------------------------------------------------
// K1: per-chunk summaries.  Unit c = (M_c = A_{l3}A_{l2}A_{l1}A_{l0},
//                                     w_c = sum of propagated u's),  l = 4c..4c+3.
__global__ __launch_bounds__(256) void k1_chunks(const float* __restrict__ A,
                                                 const float* __restrict__ x,
                                                 const float* __restrict__ Bv,
                                                 float* __restrict__ U) {
  __shared__ float P[128 * LDP];
  __shared__ float As[16 * LDA];
  const int tid = threadIdx.x;
  const int c = blockIdx.x;
  const int l0 = c * TCH;
  // init: P[:, :128] = A_{l0};  P[i][128+b] = u_{l0}[i,b]
  for (int q = 0; q < 16; ++q) {
    const int f4i = tid + 256 * q;
    const int i = f4i >> 5, c4 = (f4i & 31) * 4;
    *(float4*)(P + i * LDP + c4) = *(const float4*)(A + (size_t)l0 * NN * NN + i * NN + c4);
  }
  for (int q = 0; q < 16; ++q) {
    const int e = tid + 256 * q;
    const int i = e >> 5, b = e & 31;
    P[i * LDP + 128 + b] = Bv[l0 * NN + i] * x[l0 * NB + b];
  }
  for (int j = 1; j < TCH; ++j) {
    const int l = l0 + j;
    aug_matmul(A + (size_t)l * NN * NN, P, As);  // leading sync protects init/+= above
    for (int q = 0; q < 16; ++q) {
      const int e = tid + 256 * q;
      const int i = e >> 5, b = e & 31;
      P[i * LDP + 128 + b] += Bv[l * NN + i] * x[l * NB + b];
    }
  }
  __syncthreads();
  float* o = U + (size_t)c * UNIT;
  for (int q = 0; q < 16; ++q) {
    const int f4i = tid + 256 * q;
    const int i = f4i >> 5, c4 = (f4i & 31) * 4;
    *(float4*)(o + i * NN + c4) = *(const float4*)(P + i * LDP + c4);
  }
  for (int q = 0; q < 4; ++q) {
    const int e = tid + 256 * q;  // 1024 float4s of W
    const int i = e >> 3, b4 = (e & 7) * 4;
    *(float4*)(o + NN * NN + i * NB + b4) =
        make_float4(P[i * LDP + 128 + b4], P[i * LDP + 128 + b4 + 1],
                    P[i * LDP + 128 + b4 + 2], P[i * LDP + 128 + b4 + 3]);
  }
}

// ---------------------------------------------------------------------------
// K2: pair combine.  out[n] = child[2n+1] o child[2n]
__global__ __launch_bounds__(256) void k2_combine(const float* __restrict__ Uchild,
                                                  float* __restrict__ Uout) {
  __shared__ float P[128 * LDP];
  __shared__ float As[16 * LDA];
  const int tid = threadIdx.x;
  const int n = blockIdx.x;
  const float* lo = Uchild + (size_t)(2 * n) * UNIT;
  const float* hi = Uchild + (size_t)(2 * n + 1) * UNIT;
  for (int q = 0; q < 16; ++q) {
    const int f4i = tid + 256 * q;
    const int i = f4i >> 5, c4 = (f4i & 31) * 4;
    *(float4*)(P + i * LDP + c4) = *(const float4*)(lo + i * NN + c4);
  }
  for (int q = 0; q < 16; ++q) {
    const int e = tid + 256 * q;
    const int i = e >> 5, b = e & 31;
    P[i * LDP + 128 + b] = lo[NN * NN + i * NB + b];
  }
  aug_matmul(hi, P, As);
  for (int q = 0; q < 16; ++q) {
    const int e = tid + 256 * q;
    const int i = e >> 5, b = e & 31;
    P[i * LDP + 128 + b] += hi[NN * NN + i * NB + b];
  }
  __syncthreads();
  float* o = Uout + (size_t)n * UNIT;
  for (int q = 0; q < 16; ++q) {
    const int f4i = tid + 256 * q;
    const int i = f4i >> 5, c4 = (f4i & 31) * 4;
    *(float4*)(o + i * NN + c4) = *(const float4*)(P + i * LDP + c4);
  }
  for (int q = 0; q < 4; ++q) {
    const int e = tid + 256 * q;
    const int i = e >> 3, b4 = (e & 7) * 4;
    *(float4*)(o + NN * NN + i * NB + b4) =
        make_float4(P[i * LDP + 128 + b4], P[i * LDP + 128 + b4 + 1],
                    P[i * LDP + 128 + b4 + 2], P[i * LDP + 128 + b4 + 3]);
  }
}

// ---------------------------------------------------------------------------
// K3: per chunk, build entry state from tree (group prefix at level 5 + binary
// walk over levels 4..0), then replay the 4 timesteps and write outputs.
__global__ __launch_bounds__(128) void k3_replay(const float* __restrict__ A,
                                                 const float* __restrict__ x,
                                                 const float* __restrict__ Bv,
                                                 const float* __restrict__ U,
                                                 float* __restrict__ out) {
  __shared__ float S[128 * LDS_S];
  __shared__ float As[16 * LDA];
  const int tid = threadIdx.x;
  const int c = blockIdx.x;
  for (int q = 0; q < LDS_S; ++q) S[tid + 128 * q] = 0.f;
  __syncthreads();
  const int ri = tid >> 3, tb = tid & 7;
  const int i0 = ri * 8, b0 = tb * 4;

  // group prefix: level-5 units (base 496), groups of 32 chunks
  const int g = c >> 5;
  for (int h = 0; h < g; ++h) {
    const float* u5 = U + (size_t)(496 + h) * UNIT;
    apply_op(u5, S, As);
#pragma unroll
    for (int r = 0; r < 8; ++r) {
      const int i = i0 + r;
#pragma unroll
      for (int q = 0; q < 4; ++q)
        S[i * LDS_S + b0 + q] += u5[NN * NN + i * NB + b0 + q];
    }
    __syncthreads();
  }
  // binary walk inside the group, coarse -> fine
  const int lvlbase[5] = {0, 256, 384, 448, 480};
#pragma unroll
  for (int m = 4; m >= 0; --m) {
    if ((c >> m) & 1) {
      const float* un = U + (size_t)(lvlbase[m] + (c >> m) - 1) * UNIT;
      apply_op(un, S, As);
#pragma unroll
      for (int r = 0; r < 8; ++r) {
        const int i = i0 + r;
#pragma unroll
        for (int q = 0; q < 4; ++q)
          S[i * LDS_S + b0 + q] += un[NN * NN + i * NB + b0 + q];
      }
      __syncthreads();
    }
  }
  // replay the chunk
  for (int j = 0; j < TCH; ++j) {
    const int l = c * TCH + j;
    apply_op(A + (size_t)l * NN * NN, S, As);
#pragma unroll
    for (int r = 0; r < 8; ++r) {
      const int i = i0 + r;
      const float bvi = Bv[l * NN + i];
#pragma unroll
      for (int q = 0; q < 4; ++q)
        S[i * LDS_S + b0 + q] += bvi * x[l * NB + b0 + q];
    }
    __syncthreads();
    for (int q = 0; q < 32; ++q) {
      const int e = tid + 128 * q;  // out[l][b][n] = S[n][b]
      out[(size_t)l * (NN * NB) + e] = S[(e & 127) * LDS_S + (e >> 7)];
    }
    __syncthreads();
  }
}

// ---------------------------------------------------------------------------
extern "C" void kernel_launch(void* const* d_in, const int* in_sizes, int n_in,
                              void* d_out, int out_size, void* d_ws, size_t ws_size,
                              hipStream_t stream) {
  const float* x  = (const float*)d_in[0];  // (1024, 32)
  const float* A  = (const float*)d_in[1];  // (1024, 128, 128)
  const float* Bv = (const float*)d_in[2];  // (1024, 128)
  float* out = (float*)d_out;               // (1024, 32, 128)
  float* U = (float*)d_ws;                  // needs 504 * 20480 * 4 B = 41.3 MB

  k1_chunks<<<NCH, 256, 0, stream>>>(A, x, Bv, U);
  const int childBase[5] = {0, 256, 384, 448, 480};
  const int outBase[5]   = {256, 384, 448, 480, 496};
  const int ncomb[5]     = {128, 64, 32, 16, 8};
  for (int lvl = 0; lvl < 5; ++lvl) {
    k2_combine<<<ncomb[lvl], 256, 0, stream>>>(U + (size_t)childBase[lvl] * UNIT,
                                               U + (size_t)outBase[lvl] * UNIT);
  }
  k3_replay<<<NCH, 128, 0, stream>>>(A, x, Bv, U, out);
}

// Round 2
// 463.468 us; speedup vs baseline: 1.0095x; 1.0095x over previous
//
#include <hip/hip_runtime.h>

// HiPPO-LegS scan, fp32 chunked associative scan — round 2.
// s_t = A_t s_{t-1} + u_t, u_t[b,n] = x[t,b]*Bv[t,n], out[t,b,n] = s_t[n].
// N=128, B=32, L=1024. Chunks of 4 (256). Up-tree to level 5, then explicit
// downsweep of entry states (D1 + 4 ds levels), slim replay (4-5 matvecs).
// All A_st and their products are LOWER TRIANGULAR -> wave-uniform kt-skips
// with symmetric row pairing (balanced ~1.9x FMA savings).
// Workspace: 504 units (80KB) + entry-state arrays = 45.4 MB of d_ws.

#define NN 128
#define NB 32
#define LDP 160    // P row stride in k1 (128 mat + 32 state)
#define LDA 132    // staged A-tile stride (transposed, 16 x 132)
#define LDA2 68    // k2 staged hi-tile stride (16 x 68)
#define LDPS 164   // k2 staged lo-tile stride (16 x 164)
#define LDS_S 36   // state tile stride (128 x 36)
#define UNIT 20480 // floats per unit: 128*128 M + 128*32 w
#define WOFF 16384 // w offset inside a unit

// ---------------------------------------------------------------------------
// apply256: S (LDS, state[n][b], stride LDS_S) <- Mg (global 128x128, lower-tri) * S
// 256 threads. Wave w owns rows [16w,16w+16) u [112-16w,128-16w); per-lane 2+2 rows.
// kt-skip: lo rows need kt<=w, hi rows kt<=7-w (wave-uniform).
__device__ __forceinline__ void apply256(const float* __restrict__ Mg,
                                         float* __restrict__ S,
                                         float* __restrict__ As) {  // 2*16*LDA
  const int tid = threadIdx.x;
  const int w = tid >> 6;
  const int tq = (tid >> 3) & 7;
  const int b0 = (tid & 7) * 4;
  const int rlo = 16 * w + tq * 2;
  const int rhi = 112 - 16 * w + tq * 2;
  const int ktlo = w, kthi = 7 - w;
  float aL0[4], aL1[4], aH0[4], aH1[4];
#pragma unroll
  for (int q = 0; q < 4; ++q) { aL0[q] = 0.f; aL1[q] = 0.f; aH0[q] = 0.f; aH1[q] = 0.f; }
  const int sq = tid & 3, sib = tid >> 2;  // staging: 4 k-rows x 64 i each? -> 2 f4/thread
#pragma unroll
  for (int h = 0; h < 2; ++h) {
    const int i = sib + 64 * h;
    const float4 v = *(const float4*)(Mg + i * NN + sq * 4);
    As[(sq * 4 + 0) * LDA + i] = v.x; As[(sq * 4 + 1) * LDA + i] = v.y;
    As[(sq * 4 + 2) * LDA + i] = v.z; As[(sq * 4 + 3) * LDA + i] = v.w;
  }
  __syncthreads();
  for (int kt = 0; kt < 8; ++kt) {
    const float* Ac = As + (kt & 1) * (16 * LDA);
    if (kt < 7) {
      float* An = As + ((kt + 1) & 1) * (16 * LDA);
#pragma unroll
      for (int h = 0; h < 2; ++h) {
        const int i = sib + 64 * h;
        const float4 v = *(const float4*)(Mg + i * NN + (kt + 1) * 16 + sq * 4);
        An[(sq * 4 + 0) * LDA + i] = v.x; An[(sq * 4 + 1) * LDA + i] = v.y;
        An[(sq * 4 + 2) * LDA + i] = v.z; An[(sq * 4 + 3) * LDA + i] = v.w;
      }
    }
    const bool dlo = (kt <= ktlo), dhi = (kt <= kthi);
    if (dlo || dhi) {
#pragma unroll
      for (int kk = 0; kk < 16; ++kk) {
        const int k = kt * 16 + kk;
        const float4 sv = *(const float4*)(S + k * LDS_S + b0);
        const float sa[4] = {sv.x, sv.y, sv.z, sv.w};
        if (dlo) {
          const float2 a = *(const float2*)(Ac + kk * LDA + rlo);
#pragma unroll
          for (int q = 0; q < 4; ++q) { aL0[q] += a.x * sa[q]; aL1[q] += a.y * sa[q]; }
        }
        if (dhi) {
          const float2 a = *(const float2*)(Ac + kk * LDA + rhi);
#pragma unroll
          for (int q = 0; q < 4; ++q) { aH0[q] += a.x * sa[q]; aH1[q] += a.y * sa[q]; }
        }
      }
    }
    __syncthreads();
  }
  *(float4*)(S + rlo * LDS_S + b0)       = make_float4(aL0[0], aL0[1], aL0[2], aL0[3]);
  *(float4*)(S + (rlo + 1) * LDS_S + b0) = make_float4(aL1[0], aL1[1], aL1[2], aL1[3]);
  *(float4*)(S + rhi * LDS_S + b0)       = make_float4(aH0[0], aH0[1], aH0[2], aH0[3]);
  *(float4*)(S + (rhi + 1) * LDS_S + b0) = make_float4(aH1[0], aH1[1], aH1[2], aH1[3]);
  __syncthreads();
}

// S += w (unit w part), linear, 256 threads; caller must sync after.
__device__ __forceinline__ void add_w256(const float* __restrict__ wsrc,
                                         float* __restrict__ S) {
#pragma unroll
  for (int q = 0; q < 4; ++q) {
    const int f = threadIdx.x + 256 * q;
    const int i = f >> 3, b4 = (f & 7) * 4;
    const float4 wv = *(const float4*)(wsrc + i * NB + b4);
    float* p = S + i * LDS_S + b4;
    p[0] += wv.x; p[1] += wv.y; p[2] += wv.z; p[3] += wv.w;
  }
}

// ---------------------------------------------------------------------------
// aug512: P (LDS, 128 x LDP = [M 128 | state 32]) <- Ag (global, lower-tri) * P
// 512 threads. Wave w owns rows [8w,8w+8) u [120-8w,128-8w). tj=tid&15 owns
// cols tj*4 (A), 64+tj*4 (B), 128+tj*2 (S). P's matrix part stays lower-tri:
// lo rows (<64) have zero B-part; B-part needs kt>=4 (P[k][64+c]=0 for k<64+c).
__device__ __forceinline__ void aug512(const float* __restrict__ Ag,
                                       float* __restrict__ P,
                                       float* __restrict__ As) {  // 2*16*LDA
  const int tid = threadIdx.x;
  const int w = tid >> 6;          // 0..7
  const int tq = (tid >> 4) & 3;
  const int tj = tid & 15;
  const int rlo = 8 * w + tq * 2;
  const int rhi = 120 - 8 * w + tq * 2;
  const int ktlo = w >> 1;
  const int kthi = (127 - 8 * w) >> 4;
  float LA0[4], LA1[4], HA0[4], HA1[4], HB0[4], HB1[4];
  float LS0[2], LS1[2], HS0[2], HS1[2];
#pragma unroll
  for (int q = 0; q < 4; ++q) { LA0[q]=0.f; LA1[q]=0.f; HA0[q]=0.f; HA1[q]=0.f; HB0[q]=0.f; HB1[q]=0.f; }
  LS0[0]=LS0[1]=LS1[0]=LS1[1]=HS0[0]=HS0[1]=HS1[0]=HS1[1]=0.f;
  const int sq = tid & 3, sib = tid >> 2;  // 0..127, one f4/thread
  {
    const float4 v = *(const float4*)(Ag + sib * NN + sq * 4);
    As[(sq * 4 + 0) * LDA + sib] = v.x; As[(sq * 4 + 1) * LDA + sib] = v.y;
    As[(sq * 4 + 2) * LDA + sib] = v.z; As[(sq * 4 + 3) * LDA + sib] = v.w;
  }
  __syncthreads();
  for (int kt = 0; kt < 8; ++kt) {
    const float* Ac = As + (kt & 1) * (16 * LDA);
    if (kt < 7) {
      float* An = As + ((kt + 1) & 1) * (16 * LDA);
      const float4 v = *(const float4*)(Ag + sib * NN + (kt + 1) * 16 + sq * 4);
      An[(sq * 4 + 0) * LDA + sib] = v.x; An[(sq * 4 + 1) * LDA + sib] = v.y;
      An[(sq * 4 + 2) * LDA + sib] = v.z; An[(sq * 4 + 3) * LDA + sib] = v.w;
    }
    const bool alo = (kt <= ktlo), ahi = (kt <= kthi), bhi = ahi && (kt >= 4);
    if (alo || ahi) {
#pragma unroll
      for (int kk = 0; kk < 16; ++kk) {
        const int k = kt * 16 + kk;
        const float4 p0 = *(const float4*)(P + k * LDP + tj * 4);
        const float p0a[4] = {p0.x, p0.y, p0.z, p0.w};
        const float2 ps = *(const float2*)(P + k * LDP + 128 + tj * 2);
        if (alo) {
          const float2 a = *(const float2*)(Ac + kk * LDA + rlo);
#pragma unroll
          for (int q = 0; q < 4; ++q) { LA0[q] += a.x * p0a[q]; LA1[q] += a.y * p0a[q]; }
          LS0[0] += a.x * ps.x; LS0[1] += a.x * ps.y;
          LS1[0] += a.y * ps.x; LS1[1] += a.y * ps.y;
        }
        if (ahi) {
          const float2 a = *(const float2*)(Ac + kk * LDA + rhi);
#pragma unroll
          for (int q = 0; q < 4; ++q) { HA0[q] += a.x * p0a[q]; HA1[q] += a.y * p0a[q]; }
          HS0[0] += a.x * ps.x; HS0[1] += a.x * ps.y;
          HS1[0] += a.y * ps.x; HS1[1] += a.y * ps.y;
          if (bhi) {
            const float4 p1 = *(const float4*)(P + k * LDP + 64 + tj * 4);
            const float p1a[4] = {p1.x, p1.y, p1.z, p1.w};
#pragma unroll
            for (int q = 0; q < 4; ++q) { HB0[q] += a.x * p1a[q]; HB1[q] += a.y * p1a[q]; }
          }
        }
      }
    }
    __syncthreads();
  }
  // epilogue (B-part of lo rows is exactly zero)
  *(float4*)(P + rlo * LDP + tj * 4)       = make_float4(LA0[0], LA0[1], LA0[2], LA0[3]);
  *(float4*)(P + (rlo + 1) * LDP + tj * 4) = make_float4(LA1[0], LA1[1], LA1[2], LA1[3]);
  *(float4*)(P + rlo * LDP + 64 + tj * 4)       = make_float4(0.f, 0.f, 0.f, 0.f);
  *(float4*)(P + (rlo + 1) * LDP + 64 + tj * 4) = make_float4(0.f, 0.f, 0.f, 0.f);
  *(float2*)(P + rlo * LDP + 128 + tj * 2)       = make_float2(LS0[0], LS0[1]);
  *(float2*)(P + (rlo + 1) * LDP + 128 + tj * 2) = make_float2(LS1[0], LS1[1]);
  *(float4*)(P + rhi * LDP + tj * 4)       = make_float4(HA0[0], HA0[1], HA0[2], HA0[3]);
  *(float4*)(P + (rhi + 1) * LDP + tj * 4) = make_float4(HA1[0], HA1[1], HA1[2], HA1[3]);
  *(float4*)(P + rhi * LDP + 64 + tj * 4)       = make_float4(HB0[0], HB0[1], HB0[2], HB0[3]);
  *(float4*)(P + (rhi + 1) * LDP + 64 + tj * 4) = make_float4(HB1[0], HB1[1], HB1[2], HB1[3]);
  *(float2*)(P + rhi * LDP + 128 + tj * 2)       = make_float2(HS0[0], HS0[1]);
  *(float2*)(P + (rhi + 1) * LDP + 128 + tj * 2) = make_float2(HS1[0], HS1[1]);
  __syncthreads();
}

// ---------------------------------------------------------------------------
// K1: per-chunk summaries (M_c, w_c), chunk = 4 timesteps. 512 threads.
__global__ __launch_bounds__(512) void k1_chunks(const float* __restrict__ A,
                                                 const float* __restrict__ x,
                                                 const float* __restrict__ Bv,
                                                 float* __restrict__ U) {
  __shared__ float P[128 * LDP];
  __shared__ float As[2 * 16 * LDA];
  const int tid = threadIdx.x;
  const int c = blockIdx.x;
  const int l0 = c * 4;
#pragma unroll
  for (int q = 0; q < 8; ++q) {
    const int f4i = tid + 512 * q;
    const int i = f4i >> 5, c4 = (f4i & 31) * 4;
    *(float4*)(P + i * LDP + c4) = *(const float4*)(A + (size_t)l0 * NN * NN + i * NN + c4);
  }
#pragma unroll
  for (int q = 0; q < 8; ++q) {
    const int e = tid + 512 * q;
    const int i = e >> 5, b = e & 31;
    P[i * LDP + 128 + b] = Bv[l0 * NN + i] * x[l0 * NB + b];
  }
  for (int j = 1; j < 4; ++j) {
    const int l = l0 + j;
    aug512(A + (size_t)l * NN * NN, P, As);  // begins with stage+sync: orders init/+=
#pragma unroll
    for (int q = 0; q < 2; ++q) {
      const int f = tid + 512 * q;
      const int i = f >> 3, b4 = (f & 7) * 4;
      const float bvi = Bv[l * NN + i];
      const float4 xv = *(const float4*)(x + l * NB + b4);
      float* p = P + i * LDP + 128 + b4;
      p[0] += bvi * xv.x; p[1] += bvi * xv.y; p[2] += bvi * xv.z; p[3] += bvi * xv.w;
    }
  }
  __syncthreads();
  float* o = U + (size_t)c * UNIT;
#pragma unroll
  for (int q = 0; q < 8; ++q) {
    const int f4i = tid + 512 * q;
    const int i = f4i >> 5, c4 = (f4i & 31) * 4;
    *(float4*)(o + i * NN + c4) = *(const float4*)(P + i * LDP + c4);
  }
#pragma unroll
  for (int q = 0; q < 2; ++q) {
    const int f = tid + 512 * q;
    const int i = f >> 3, b4 = (f & 7) * 4;
    *(float4*)(o + WOFF + i * NB + b4) = *(const float4*)(P + i * LDP + 128 + b4);
  }
}

// ---------------------------------------------------------------------------
// K2: pair combine, row-split x2, streamed k-tiles. out[node] = hi o lo.
// Block rs covers rows [32rs,32rs+32) u [96-32rs,128-32rs); wave W = rs*4+(tid>>6).
__global__ __launch_bounds__(256) void k2_combine(const float* __restrict__ Uc,
                                                  float* __restrict__ Uo) {
  __shared__ float Ah[2 * 16 * LDA2];
  __shared__ float Ps[2 * 16 * LDPS];
  const int tid = threadIdx.x;
  const int node = blockIdx.x >> 1, rs = blockIdx.x & 1;
  const float* lo = Uc + (size_t)(2 * node) * UNIT;
  const float* hi = Uc + (size_t)(2 * node + 1) * UNIT;
  float* o = Uo + (size_t)node * UNIT;
  const int W = rs * 4 + (tid >> 6);
  const int tq = (tid >> 4) & 3;
  const int tj = tid & 15;
  const int grlo = 8 * W + tq * 2;
  const int grhi = 120 - 8 * W + tq * 2;
  const int b1 = 32 * rs, b2 = 96 - 32 * rs;
  const int llo = grlo - b1;
  const int lhi = grhi - b2 + 32;
  const int ktlo = W >> 1;
  const int kthi = (127 - 8 * W) >> 4;
  float LA0[4], LA1[4], HA0[4], HA1[4], HB0[4], HB1[4];
  float LS0[2], LS1[2], HS0[2], HS1[2];
#pragma unroll
  for (int q = 0; q < 4; ++q) { LA0[q]=0.f; LA1[q]=0.f; HA0[q]=0.f; HA1[q]=0.f; HB0[q]=0.f; HB1[q]=0.f; }
  LS0[0]=LS0[1]=LS1[0]=LS1[1]=HS0[0]=HS0[1]=HS1[0]=HS1[1]=0.f;
  const int sq = tid & 3, sib = tid >> 2;  // 0..63
  const int grow = (sib < 32) ? (b1 + sib) : (b2 + sib - 32);

#define K2_STAGE(BUF, KT)                                                        \
  {                                                                              \
    const float4 v = *(const float4*)(hi + grow * NN + (KT) * 16 + sq * 4);      \
    float* Ab = Ah + (BUF) * (16 * LDA2);                                        \
    Ab[(sq * 4 + 0) * LDA2 + sib] = v.x; Ab[(sq * 4 + 1) * LDA2 + sib] = v.y;    \
    Ab[(sq * 4 + 2) * LDA2 + sib] = v.z; Ab[(sq * 4 + 3) * LDA2 + sib] = v.w;    \
    float* Pb = Ps + (BUF) * (16 * LDPS);                                        \
    _Pragma("unroll")                                                            \
    for (int h = 0; h < 3; ++h) {                                                \
      const int idx = tid + 256 * h;                                             \
      if (idx < 640) {                                                           \
        const int kk = idx / 40;                                                 \
        const int c4 = (idx - kk * 40) * 4;                                      \
        const int k = (KT) * 16 + kk;                                            \
        const float4 pv = (c4 < 128) ? *(const float4*)(lo + k * NN + c4)        \
                                     : *(const float4*)(lo + WOFF + k * NB + (c4 - 128)); \
        *(float4*)(Pb + kk * LDPS + c4) = pv;                                    \
      }                                                                          \
    }                                                                            \
  }

  K2_STAGE(0, 0);
  __syncthreads();
  for (int kt = 0; kt < 8; ++kt) {
    const float* Ab = Ah + (kt & 1) * (16 * LDA2);
    const float* Pb = Ps + (kt & 1) * (16 * LDPS);
    if (kt < 7) { K2_STAGE((kt + 1) & 1, kt + 1); }
    const bool alo = (kt <= ktlo), ahi = (kt <= kthi), bhi = ahi && (kt >= 4);
    if (alo || ahi) {
#pragma unroll
      for (int kk = 0; kk < 16; ++kk) {
        const float4 p0 = *(const float4*)(Pb + kk * LDPS + tj * 4);
        const float p0a[4] = {p0.x, p0.y, p0.z, p0.w};
        const float2 ps = *(const float2*)(Pb + kk * LDPS + 128 + tj * 2);
        if (alo) {
          const float2 a = *(const float2*)(Ab + kk * LDA2 + llo);
#pragma unroll
          for (int q = 0; q < 4; ++q) { LA0[q] += a.x * p0a[q]; LA1[q] += a.y * p0a[q]; }
          LS0[0] += a.x * ps.x; LS0[1] += a.x * ps.y;
          LS1[0] += a.y * ps.x; LS1[1] += a.y * ps.y;
        }
        if (ahi) {
          const float2 a = *(const float2*)(Ab + kk * LDA2 + lhi);
#pragma unroll
          for (int q = 0; q < 4; ++q) { HA0[q] += a.x * p0a[q]; HA1[q] += a.y * p0a[q]; }
          HS0[0] += a.x * ps.x; HS0[1] += a.x * ps.y;
          HS1[0] += a.y * ps.x; HS1[1] += a.y * ps.y;
          if (bhi) {
            const float4 p1 = *(const float4*)(Pb + kk * LDPS + 64 + tj * 4);
            const float p1a[4] = {p1.x, p1.y, p1.z, p1.w};
#pragma unroll
            for (int q = 0; q < 4; ++q) { HB0[q] += a.x * p1a[q]; HB1[q] += a.y * p1a[q]; }
          }
        }
      }
    }
    __syncthreads();
  }
#undef K2_STAGE
  const float* hw = hi + WOFF;
  // lo rows
  *(float4*)(o + grlo * NN + tj * 4)       = make_float4(LA0[0], LA0[1], LA0[2], LA0[3]);
  *(float4*)(o + (grlo + 1) * NN + tj * 4) = make_float4(LA1[0], LA1[1], LA1[2], LA1[3]);
  *(float4*)(o + grlo * NN + 64 + tj * 4)       = make_float4(0.f, 0.f, 0.f, 0.f);
  *(float4*)(o + (grlo + 1) * NN + 64 + tj * 4) = make_float4(0.f, 0.f, 0.f, 0.f);
  o[WOFF + grlo * NB + tj * 2 + 0]       = LS0[0] + hw[grlo * NB + tj * 2 + 0];
  o[WOFF + grlo * NB + tj * 2 + 1]       = LS0[1] + hw[grlo * NB + tj * 2 + 1];
  o[WOFF + (grlo + 1) * NB + tj * 2 + 0] = LS1[0] + hw[(grlo + 1) * NB + tj * 2 + 0];
  o[WOFF + (grlo + 1) * NB + tj * 2 + 1] = LS1[1] + hw[(grlo + 1) * NB + tj * 2 + 1];
  // hi rows
  *(float4*)(o + grhi * NN + tj * 4)       = make_float4(HA0[0], HA0[1], HA0[2], HA0[3]);
  *(float4*)(o + (grhi + 1) * NN + tj * 4) = make_float4(HA1[0], HA1[1], HA1[2], HA1[3]);
  *(float4*)(o + grhi * NN + 64 + tj * 4)       = make_float4(HB0[0], HB0[1], HB0[2], HB0[3]);
  *(float4*)(o + (grhi + 1) * NN + 64 + tj * 4) = make_float4(HB1[0], HB1[1], HB1[2], HB1[3]);
  o[WOFF + grhi * NB + tj * 2 + 0]       = HS0[0] + hw[grhi * NB + tj * 2 + 0];
  o[WOFF + grhi * NB + tj * 2 + 1]       = HS0[1] + hw[grhi * NB + tj * 2 + 1];
  o[WOFF + (grhi + 1) * NB + tj * 2 + 0] = HS1[0] + hw[(grhi + 1) * NB + tj * 2 + 0];
  o[WOFF + (grhi + 1) * NB + tj * 2 + 1] = HS1[1] + hw[(grhi + 1) * NB + tj * 2 + 1];
}

// ---------------------------------------------------------------------------
// D1: entry states of the 8 level-5 groups (block h scans groups 0..h-1).
__global__ __launch_bounds__(256) void d1_groups(const float* __restrict__ U,
                                                 float* __restrict__ E5) {
  __shared__ float S[128 * LDS_S];
  __shared__ float As[2 * 16 * LDA];
  const int tid = threadIdx.x;
  const int h = blockIdx.x;
  for (int idx = tid; idx < 128 * LDS_S; idx += 256) S[idx] = 0.f;
  for (int i = 0; i < h; ++i) {
    const float* u5 = U + (size_t)(496 + i) * UNIT;
    apply256(u5, S, As);           // starts with stage+sync: orders prior writes
    add_w256(u5 + WOFF, S);
    __syncthreads();
  }
  __syncthreads();
#pragma unroll
  for (int q = 0; q < 4; ++q) {
    const int f = tid + 256 * q;
    const int i = f >> 3, b4 = (f & 7) * 4;
    *(float4*)(E5 + (size_t)h * 4096 + i * NB + b4) = *(const float4*)(S + i * LDS_S + b4);
  }
}

// ---------------------------------------------------------------------------
// Downsweep one level: Eout[n] = (n even) ? Eprev[n/2] : U[ubase+n-1] applied to Eprev[n/2].
__global__ __launch_bounds__(256) void ds_level(const float* __restrict__ U, int ubase,
                                                const float* __restrict__ Eprev,
                                                float* __restrict__ Eout) {
  __shared__ float S[128 * LDS_S];
  __shared__ float As[2 * 16 * LDA];
  const int tid = threadIdx.x;
  const int n = blockIdx.x;
  const float* ep = Eprev + (size_t)(n >> 1) * 4096;
  float* eo = Eout + (size_t)n * 4096;
  if ((n & 1) == 0) {
#pragma unroll
    for (int q = 0; q < 4; ++q) {
      const int f4 = tid + 256 * q;
      *(float4*)(eo + f4 * 4) = *(const float4*)(ep + f4 * 4);
    }
    return;
  }
#pragma unroll
  for (int q = 0; q < 4; ++q) {
    const int f = tid + 256 * q;
    const int i = f >> 3, b4 = (f & 7) * 4;
    *(float4*)(S + i * LDS_S + b4) = *(const float4*)(ep + i * NB + b4);
  }
  const float* um = U + (size_t)(ubase + n - 1) * UNIT;
  apply256(um, S, As);
  add_w256(um + WOFF, S);
  __syncthreads();
#pragma unroll
  for (int q = 0; q < 4; ++q) {
    const int f = tid + 256 * q;
    const int i = f >> 3, b4 = (f & 7) * 4;
    *(float4*)(eo + i * NB + b4) = *(const float4*)(S + i * LDS_S + b4);
  }
}

// ---------------------------------------------------------------------------
// K3: chunk replay. Entry = E1[c/2], plus U0[c-1] if c odd; then 4 timesteps.
__global__ __launch_bounds__(256) void k3_replay(const float* __restrict__ A,
                                                 const float* __restrict__ x,
                                                 const float* __restrict__ Bv,
                                                 const float* __restrict__ U,
                                                 const float* __restrict__ E1,
                                                 float* __restrict__ out) {
  __shared__ float S[128 * LDS_S];
  __shared__ float As[2 * 16 * LDA];
  const int tid = threadIdx.x;
  const int c = blockIdx.x;
  const float* e1 = E1 + (size_t)(c >> 1) * 4096;
#pragma unroll
  for (int q = 0; q < 4; ++q) {
    const int f = tid + 256 * q;
    const int i = f >> 3, b4 = (f & 7) * 4;
    *(float4*)(S + i * LDS_S + b4) = *(const float4*)(e1 + i * NB + b4);
  }
  if (c & 1) {
    const float* u0 = U + (size_t)(c - 1) * UNIT;
    apply256(u0, S, As);
    add_w256(u0 + WOFF, S);
    __syncthreads();
  }
  for (int j = 0; j < 4; ++j) {
    const int l = c * 4 + j;
    apply256(A + (size_t)l * NN * NN, S, As);
#pragma unroll
    for (int q = 0; q < 4; ++q) {
      const int f = tid + 256 * q;
      const int i = f >> 3, b4 = (f & 7) * 4;
      const float bvi = Bv[l * NN + i];
      const float4 xv = *(const float4*)(x + l * NB + b4);
      float* p = S + i * LDS_S + b4;
      p[0] += bvi * xv.x; p[1] += bvi * xv.y; p[2] += bvi * xv.z; p[3] += bvi * xv.w;
    }
    __syncthreads();
#pragma unroll
    for (int q = 0; q < 16; ++q) {
      const int e = tid + 256 * q;  // out[l][b][n] = S[n][b]
      out[(size_t)l * (NN * NB) + e] = S[(e & 127) * LDS_S + (e >> 7)];
    }
    // next apply256's leading stage+sync orders these reads vs S updates
  }
}

// ---------------------------------------------------------------------------
extern "C" void kernel_launch(void* const* d_in, const int* in_sizes, int n_in,
                              void* d_out, int out_size, void* d_ws, size_t ws_size,
                              hipStream_t stream) {
  const float* x  = (const float*)d_in[0];  // (1024, 32)
  const float* A  = (const float*)d_in[1];  // (1024, 128, 128)  lower-triangular
  const float* Bv = (const float*)d_in[2];  // (1024, 128)
  float* out = (float*)d_out;               // (1024, 32, 128)
  float* U = (float*)d_ws;                  // 504 units + entry states = 45.4 MB

  const size_t E5o = 504ull * UNIT;
  const size_t E4o = E5o + 8ull * 4096;
  const size_t E3o = E4o + 16ull * 4096;
  const size_t E2o = E3o + 32ull * 4096;
  const size_t E1o = E2o + 64ull * 4096;

  k1_chunks<<<256, 512, 0, stream>>>(A, x, Bv, U);
  // up-tree: L0->L1 (128 nodes), ..., L4->L5 (8 nodes); grid = nodes*2 (row-split)
  k2_combine<<<256, 256, 0, stream>>>(U,                      U + 256ull * UNIT);
  k2_combine<<<128, 256, 0, stream>>>(U + 256ull * UNIT,      U + 384ull * UNIT);
  k2_combine<<< 64, 256, 0, stream>>>(U + 384ull * UNIT,      U + 448ull * UNIT);
  k2_combine<<< 32, 256, 0, stream>>>(U + 448ull * UNIT,      U + 480ull * UNIT);
  k2_combine<<< 16, 256, 0, stream>>>(U + 480ull * UNIT,      U + 496ull * UNIT);
  // downsweep of entry states
  d1_groups<<<8, 256, 0, stream>>>(U, U + E5o);
  ds_level<<< 16, 256, 0, stream>>>(U, 480, U + E5o, U + E4o);
  ds_level<<< 32, 256, 0, stream>>>(U, 448, U + E4o, U + E3o);
  ds_level<<< 64, 256, 0, stream>>>(U, 384, U + E3o, U + E2o);
  ds_level<<<128, 256, 0, stream>>>(U, 256, U + E2o, U + E1o);
  // replay
  k3_replay<<<256, 256, 0, stream>>>(A, x, Bv, U, U + E1o, out);
}